// Round 2
// baseline (240.887 us; speedup 1.0000x reference)
//
#include <hip/hip_runtime.h>
#include <math.h>

// ============================================================================
// WaveletBasis as bf16 MFMA GEMM: M=32768(B), N=64(O), K=1024*9.
// K layout: 128 "runs" of 72 k-values, run R = features [8R,8R+8). Within a
// run, feature pair p occupies shorts [18p,18p+18):
//   [basis(f_even) n=0..7 | x_even | x_odd | basis(f_odd) n=0..7]
// Chunk c = runs [4c,4c+4) = features [32c,32c+32) = 9 K32-steps.
// A tile physical layout: uint4 idx = step*256 + octet_group*64 + row, where
// K32-step s = {run q octet s : q=0..3} and lane-group q of the MFMA A-frag
// reads octet-group q. Consecutive lanes read contiguous uint4s -> A reads
// are bank-clean by construction (no swizzle needed).
//
// ROUND 4 resubmit (round-4 bench died to container-acquire infra failure;
// kernel re-audited: barriers uniform, LDS in bounds, layouts re-derived.
// Removed the round-4 XOR swizzle -- it only permuted uint4s within aligned
// 256B blocks, a bank no-op; round-3's 9M conflicts were the epilogue
// partial-C LDS traffic, which this structure deletes entirely).
//
// Structure vs round 3 (which was latency-bound: MfmaUtil 17, VALUBusy 37,
// Occupancy 19% => 2 waves/SIMD, ~46% stall):
//  - 512-thread blocks, waves = 2(M-half 32 rows) x 4(N-quarter 16 cols),
//    each wave accumulates FULL K for its strip: no cross-wave K-reduction,
//    acc = 2 f32x4, direct global stores. 16 waves/CU = 4 waves/SIMD.
//  - builder task = half-run (4 features) per thread; 512 tasks = 512 thr.
//  - double-buffered A, one barrier per chunk (unchanged discipline).
// ============================================================================

typedef __attribute__((ext_vector_type(8))) short short8;
typedef __attribute__((ext_vector_type(4))) float f32x4;

__device__ __forceinline__ unsigned int f2bf(float f) {
  unsigned int u = __float_as_uint(f);
  u += 0x7FFFu + ((u >> 16) & 1u);   // RNE; finite inputs
  return u >> 16;
}

// 4 dwords = 8 bf16 basis values (n=0..7) as a function of bucket j.
__device__ __forceinline__ void gen_basis(int j, unsigned int* d) {
  d[0] = (j < 4) ? 0x3F803F80u : 0xBF803F80u;                  // [phi=1, psi0=+-1]
  unsigned int sq1 = (j & 2) ? 0xBFB5u : 0x3FB5u;              // +-sqrt2
  d[1] = (j & 4) ? (sq1 << 16) : sq1;                          // one-hot k1=j>>2
  unsigned long long sd2 = (j & 1) ? 0xC000ull : 0x4000ull;    // +-2
  unsigned long long d23 = sd2 << ((j & 6) << 3);              // << 16*(j>>1)
  d[2] = (unsigned int)d23;
  d[3] = (unsigned int)(d23 >> 32);
}

#define BARRIER() __asm__ volatile("s_waitcnt lgkmcnt(0)\n\ts_barrier" ::: "memory")

// ---------------------------------------------------------------------------
// Builder: 4 features (pairs 2h,2h+1 of one run) for one row -> 18 dwords ->
// 4 uint4 + 1 uint2 into the A tile. dst already includes the (run,row)
// offset; writes land at dst[gg*256] (+8B half-quad at gg=4).
// Same numerics as round 3 (fast tanh + rare ref-fidelity fixer).
// ---------------------------------------------------------------------------
__device__ __forceinline__ void build_half(const float4& xq,
                                           uint4* __restrict__ dst, int h) {
  float xv[4] = {xq.x, xq.y, xq.z, xq.w};
  float t8v[4];
  unsigned int bad = 0;
#pragma unroll
  for (int ff = 0; ff < 4; ++ff) {
    float e = __expf(2.0f * xv[ff]);                 // t8 = 8*e/(e+1) = 8 - 8/(e+1)
    float r = __builtin_amdgcn_rcpf(e + 1.0f);
    float t8 = __builtin_fmaf(-8.0f, r, 8.0f);
    float rn = rintf(t8);
    if (fabsf(t8 - rn) < 3e-5f) bad |= 1u << ff;
    t8v[ff] = t8;
  }
  if (__builtin_expect(bad != 0, 0)) {
#pragma unroll
    for (int ff = 0; ff < 4; ++ff)
      if (bad & (1u << ff)) {
        float tf = (float)tanh((double)xv[ff]);      // ref-fidelity fallback
        t8v[ff] = ((tf + 1.0f) * 0.5f) * 8.0f;       // exact ref f32 pipeline
      }
  }
  unsigned int dw[18];
#pragma unroll
  for (int p = 0; p < 2; ++p) {
    int je = (int)t8v[2 * p];     je = je > 7 ? 7 : je;   // t8 in [0,8]
    int jo = (int)t8v[2 * p + 1]; jo = jo > 7 ? 7 : jo;
    gen_basis(je, &dw[9 * p]);
    dw[9 * p + 4] = f2bf(xv[2 * p]) | (f2bf(xv[2 * p + 1]) << 16);
    gen_basis(jo, &dw[9 * p + 5]);
  }
  // h=0: run dwords 0..17  -> full quads gg=0..3 (local dw 0..15) + gg4.xy
  // h=1: run dwords 18..35 -> gg4.zw (local dw 0..1) + full quads gg=5..8
  const int db = h ? 2 : 0;
  const int gb = h ? 5 : 0;
#pragma unroll
  for (int k = 0; k < 4; ++k) {
    uint4 qv;
    qv.x = dw[db + 4 * k];     qv.y = dw[db + 4 * k + 1];
    qv.z = dw[db + 4 * k + 2]; qv.w = dw[db + 4 * k + 3];
    dst[(gb + k) * 256] = qv;
  }
  uint2 hv;
  if (h) { hv.x = dw[0];  hv.y = dw[1];  }
  else   { hv.x = dw[16]; hv.y = dw[17]; }
  ((uint2*)(dst + 4 * 256))[h] = hv;
}

// ---------------------------------------------------------------------------
// K1: W swizzle into MFMA B-fragment order under the run/pair K layout.
// Wsw[(g*4+t)*64 + l] = octet j=g%9 of run R=(g/9)*4+(l>>4), col o=t*16+(l&15)
// ---------------------------------------------------------------------------
__global__ __launch_bounds__(256) void build_w(const float* __restrict__ coeffs,
                                               const float* __restrict__ bw,
                                               uint4* __restrict__ Wsw) {
  const int l = threadIdx.x & 63;
  const int t = threadIdx.x >> 6;   // 0..3
  const int g = blockIdx.x;         // 0..287
  const int c = g / 9, j = g - c * 9;
  const int R = c * 4 + (l >> 4);
  const int o = t * 16 + (l & 15);
  unsigned int dwv[4];
#pragma unroll
  for (int jj = 0; jj < 8; ++jj) {
    int d = 8 * j + jj;             // run-local short index 0..71
    int p = d / 18;
    int e = d - p * 18;
    int f, n;
    if (e < 8)       { f = 8 * R + 2 * p;     n = e; }
    else if (e == 8) { f = 8 * R + 2 * p;     n = 8; }
    else if (e == 9) { f = 8 * R + 2 * p + 1; n = 8; }
    else             { f = 8 * R + 2 * p + 1; n = e - 10; }
    float v = (n < 8) ? coeffs[(f * 64 + o) * 8 + n] : bw[f * 64 + o];
    unsigned int hh = f2bf(v);
    if (jj & 1) dwv[jj >> 1] |= hh << 16; else dwv[jj >> 1] = hh;
  }
  uint4 qq; qq.x = dwv[0]; qq.y = dwv[1]; qq.z = dwv[2]; qq.w = dwv[3];
  Wsw[(g * 4 + t) * 64 + l] = qq;
}

// ---------------------------------------------------------------------------
// K2: 512 blocks x 512 thr. Block = 64 rows x 64 cols.
// Wave w: MFMA strip rows [32*(w>>2), +32), cols [16*(w&3), +16), full K.
// Builder role: run r=w&3, half h=w>>2, row = lane.
// LDS: 2 x 36 KB A double-buffer, one barrier per chunk.
// ---------------------------------------------------------------------------
__global__ __launch_bounds__(512, 4) void wavelet_gemm(const float* __restrict__ x,
                                                       const uint4* __restrict__ Wsw,
                                                       float* __restrict__ out,
                                                       int out_size) {
  __shared__ uint4 Albuf[2 * 9 * 256];   // 72 KB
  const int tid = threadIdx.x;
  const int l = tid & 63;
  const int w = tid >> 6;            // wave 0..7
  const int q = l >> 4;              // k-octet group (= run within chunk)
  const int mm = l & 15;
  const int mh = w >> 2;             // M-half: rows 32*mh..
  const int nq = w & 3;              // N-quarter: cols 16*nq..
  const int r = w & 3;               // builder run
  const int h = w >> 2;              // builder pair-half
  const int m = l;                   // builder row 0..63
  const long rowbase = (long)blockIdx.x * 64;

  const int wr_off  = r * 64 + m;               // builder (run,row) uint4 offset
  const int rd_base = q * 64 + mh * 32 + mm;    // reader (octet,row) uint4 offset

  f32x4 acc0 = (f32x4){0.f, 0.f, 0.f, 0.f};
  f32x4 acc1 = (f32x4){0.f, 0.f, 0.f, 0.f};

  const float* xrow = x + (rowbase + m) * 1024 + r * 8 + h * 4;

  float4 xa = *(const float4*)(xrow);          // chunk 0
  build_half(xa, Albuf + wr_off, h);           // chunk 0 -> buf0
  xa = *(const float4*)(xrow + 32);            // x for chunk 1
  BARRIER();

  for (int c = 0; c < 32; ++c) {
    uint4* cur = Albuf + (c & 1) * 2304;
    uint4* nxt = Albuf + ((c + 1) & 1) * 2304;
    // ---- B for this chunk (wave's 16-col slice, 9 steps; L2-hot) ----------
    uint4 Bv[9];
#pragma unroll
    for (int s = 0; s < 9; ++s)
      Bv[s] = Wsw[((c * 9 + s) * 4 + nq) * 64 + l];
    // ---- builder for chunk c+1 into the other buffer ----------------------
    if (c + 1 < 32) {
      build_half(xa, nxt + wr_off, h);
      if (c + 2 < 32) xa = *(const float4*)(xrow + (c + 2) * 32);
    }
    // ---- MFMA: full K of this chunk for the wave's 32x16 strip ------------
#pragma unroll
    for (int s = 0; s < 9; ++s) {
      const uint4* rb = cur + s * 256 + rd_base;
      short8 a0 = __builtin_bit_cast(short8, rb[0]);
      short8 a1 = __builtin_bit_cast(short8, rb[16]);   // rows +16
      short8 Bt = __builtin_bit_cast(short8, Bv[s]);
      acc0 = __builtin_amdgcn_mfma_f32_16x16x32_bf16(a0, Bt, acc0, 0, 0, 0);
      acc1 = __builtin_amdgcn_mfma_f32_16x16x32_bf16(a1, Bt, acc1, 0, 0, 0);
    }
    BARRIER();   // writes to nxt visible; reads of cur drained
  }

  // ---- epilogue: direct stores, no cross-wave reduction -------------------
  // acc0[j] -> row 32*mh + 4*q + j, col 16*nq + mm;  acc1: rows +16.
  float* og = out + (size_t)rowbase * 64;
  const int col  = nq * 16 + mm;
  const int row0 = mh * 32 + q * 4;
#pragma unroll
  for (int j = 0; j < 4; ++j) og[(row0 + j) * 64 + col] = acc0[j];
#pragma unroll
  for (int j = 0; j < 4; ++j) og[(row0 + 16 + j) * 64 + col] = acc1[j];
  if (blockIdx.x == 0 && tid == 0) out[out_size - 1] = 0.0f;  // kl = 0
}

extern "C" void kernel_launch(void* const* d_in, const int* in_sizes, int n_in,
                              void* d_out, int out_size, void* d_ws, size_t ws_size,
                              hipStream_t stream) {
  const float* x      = (const float*)d_in[0];   // [32768,1024] f32
  const float* coeffs = (const float*)d_in[1];   // [1024,64,8] f32
  const float* bw     = (const float*)d_in[2];   // [1024,64] f32
  uint4* Wsw = (uint4*)d_ws;                     // 288*4*64*16 = 1.125 MiB
  float* out = (float*)d_out;

  build_w<<<288, 256, 0, stream>>>(coeffs, bw, Wsw);
  wavelet_gemm<<<512, 512, 0, stream>>>(x, (const uint4*)Wsw, out, out_size);
}

// Round 3
// 225.311 us; speedup vs baseline: 1.0691x; 1.0691x over previous
//
#include <hip/hip_runtime.h>
#include <math.h>

// ============================================================================
// WaveletBasis as bf16 MFMA GEMM: M=32768(B), N=64(O), K=1024*9.
// K layout: 128 "runs" of 72 k-values, run R = features [8R,8R+8). Within a
// run, feature pair p occupies shorts [18p,18p+18):
//   [basis(f_even) n=0..7 | x_even | x_odd | basis(f_odd) n=0..7]
// Chunk c = runs [4c,4c+4) = features [32c,32c+32) = 9 K32-steps.
// A tile: uint4 idx = step*256 + run_local*64 + row (row 0..63, run_local
// 0..3). K16-half of MFMA (s,u): lane hi=l>>5 -> run_local 2u+hi, octet s.
//
// ROUND 5: round 4 raised occupancy (19->38%) and killed conflicts (9M->0.5M)
// but dur flat at 100us: the 8-wave full-K split amplified LDS A-reads x4
// (147KB/blk/chunk ~ 50us of LDS time) and B L2-traffic x2 (~35us), and
// VGPR=60 shows the compiler sank Bv[9] loads into the MFMA chain (exposed
// L2 latency per step). This round:
//  - waves = nq(2: 32-col half) x ks(4: K-step quarter), each wave 64 rows x
//    32 cols, 32x32x16 MFMA: A-read amp 2 (108KB/blk/chunk), B amp 1
//    (36KB/blk/chunk -> 0.6GB L2 total), half the MFMA/ds_read instructions.
//  - Bv is <=6 uint4/wave; pinned in regs between builder and MFMA via
//    empty-asm "+v" so loads complete early and are never re-issued.
//  - 4-way ks reduction via LDS once per block (conflict-free layout).
//  - builder, A layout, double-buffer, 1 barrier/chunk unchanged.
// ============================================================================

typedef __attribute__((ext_vector_type(8))) short short8;
typedef __attribute__((ext_vector_type(4))) float f32x4;
typedef __attribute__((ext_vector_type(16))) float f32x16;

__device__ __forceinline__ unsigned int f2bf(float f) {
  unsigned int u = __float_as_uint(f);
  u += 0x7FFFu + ((u >> 16) & 1u);   // RNE; finite inputs
  return u >> 16;
}

// 4 dwords = 8 bf16 basis values (n=0..7) as a function of bucket j.
__device__ __forceinline__ void gen_basis(int j, unsigned int* d) {
  d[0] = (j < 4) ? 0x3F803F80u : 0xBF803F80u;                  // [phi=1, psi0=+-1]
  unsigned int sq1 = (j & 2) ? 0xBFB5u : 0x3FB5u;              // +-sqrt2
  d[1] = (j & 4) ? (sq1 << 16) : sq1;                          // one-hot k1=j>>2
  unsigned long long sd2 = (j & 1) ? 0xC000ull : 0x4000ull;    // +-2
  unsigned long long d23 = sd2 << ((j & 6) << 3);              // << 16*(j>>1)
  d[2] = (unsigned int)d23;
  d[3] = (unsigned int)(d23 >> 32);
}

#define BARRIER() __asm__ volatile("s_waitcnt lgkmcnt(0)\n\ts_barrier" ::: "memory")
// Pin a uint4 into VGPRs at this point: forces the load to have completed
// (vmcnt wait) and forbids the compiler from sinking/reloading it later.
#define KEEP4(v) __asm__ volatile("" : "+v"((v).x), "+v"((v).y), "+v"((v).z), "+v"((v).w))

// ---------------------------------------------------------------------------
// Builder: 4 features (pairs 2h,2h+1 of one run) for one row -> 18 dwords ->
// 4 uint4 + 1 uint2 into the A tile. dst already includes the (run,row)
// offset; writes land at dst[gg*256] (+8B half-quad at gg=4).
// Numerics unchanged (fast tanh + rare ref-fidelity fixer).
// ---------------------------------------------------------------------------
__device__ __forceinline__ void build_half(const float4& xq,
                                           uint4* __restrict__ dst, int h) {
  float xv[4] = {xq.x, xq.y, xq.z, xq.w};
  float t8v[4];
  unsigned int bad = 0;
#pragma unroll
  for (int ff = 0; ff < 4; ++ff) {
    float e = __expf(2.0f * xv[ff]);                 // t8 = 8*e/(e+1) = 8 - 8/(e+1)
    float r = __builtin_amdgcn_rcpf(e + 1.0f);
    float t8 = __builtin_fmaf(-8.0f, r, 8.0f);
    float rn = rintf(t8);
    if (fabsf(t8 - rn) < 3e-5f) bad |= 1u << ff;
    t8v[ff] = t8;
  }
  if (__builtin_expect(bad != 0, 0)) {
#pragma unroll
    for (int ff = 0; ff < 4; ++ff)
      if (bad & (1u << ff)) {
        float tf = (float)tanh((double)xv[ff]);      // ref-fidelity fallback
        t8v[ff] = ((tf + 1.0f) * 0.5f) * 8.0f;       // exact ref f32 pipeline
      }
  }
  unsigned int dw[18];
#pragma unroll
  for (int p = 0; p < 2; ++p) {
    int je = (int)t8v[2 * p];     je = je > 7 ? 7 : je;   // t8 in [0,8]
    int jo = (int)t8v[2 * p + 1]; jo = jo > 7 ? 7 : jo;
    gen_basis(je, &dw[9 * p]);
    dw[9 * p + 4] = f2bf(xv[2 * p]) | (f2bf(xv[2 * p + 1]) << 16);
    gen_basis(jo, &dw[9 * p + 5]);
  }
  // h=0: run dwords 0..17  -> full quads gg=0..3 (local dw 0..15) + gg4.xy
  // h=1: run dwords 18..35 -> gg4.zw (local dw 0..1) + full quads gg=5..8
  const int db = h ? 2 : 0;
  const int gb = h ? 5 : 0;
#pragma unroll
  for (int k = 0; k < 4; ++k) {
    uint4 qv;
    qv.x = dw[db + 4 * k];     qv.y = dw[db + 4 * k + 1];
    qv.z = dw[db + 4 * k + 2]; qv.w = dw[db + 4 * k + 3];
    dst[(gb + k) * 256] = qv;
  }
  uint2 hv;
  if (h) { hv.x = dw[0];  hv.y = dw[1];  }
  else   { hv.x = dw[16]; hv.y = dw[17]; }
  ((uint2*)(dst + 4 * 256))[h] = hv;
}

// ---------------------------------------------------------------------------
// K1: W into 32x32x16 B-fragment order. Fragment (c,s,u,nq) at
// Bsw[((c*9+s)*4 + 2u + nq)*64 + l]: lane l holds col o = 32nq+(l&31),
// k = octet s of run R = 4c+2u+(l>>5), elems jj=0..7 packed 2/dword in
// ascending k. Block g=(c,s) 0..287, wave t'=2u+nq (0..3).
// ---------------------------------------------------------------------------
__global__ __launch_bounds__(256) void build_w(const float* __restrict__ coeffs,
                                               const float* __restrict__ bw,
                                               uint4* __restrict__ Wsw) {
  const int l = threadIdx.x & 63;
  const int t = threadIdx.x >> 6;   // t' = 2u+nq, 0..3
  const int g = blockIdx.x;         // 0..287
  const int c = g / 9, j = g - c * 9;
  const int u = t >> 1, nq = t & 1;
  const int R = c * 4 + 2 * u + (l >> 5);
  const int o = nq * 32 + (l & 31);
  unsigned int dwv[4];
#pragma unroll
  for (int jj = 0; jj < 8; ++jj) {
    int d = 8 * j + jj;             // run-local short index 0..71
    int p = d / 18;
    int e = d - p * 18;
    int f, n;
    if (e < 8)       { f = 8 * R + 2 * p;     n = e; }
    else if (e == 8) { f = 8 * R + 2 * p;     n = 8; }
    else if (e == 9) { f = 8 * R + 2 * p + 1; n = 8; }
    else             { f = 8 * R + 2 * p + 1; n = e - 10; }
    float v = (n < 8) ? coeffs[(f * 64 + o) * 8 + n] : bw[f * 64 + o];
    unsigned int hh = f2bf(v);
    if (jj & 1) dwv[jj >> 1] |= hh << 16; else dwv[jj >> 1] = hh;
  }
  uint4 qq; qq.x = dwv[0]; qq.y = dwv[1]; qq.z = dwv[2]; qq.w = dwv[3];
  Wsw[(g * 4 + t) * 64 + l] = qq;
}

#define MFMA32(A, B, C) __builtin_amdgcn_mfma_f32_32x32x16_bf16( \
    __builtin_bit_cast(short8, (A)), __builtin_bit_cast(short8, (B)), (C), 0, 0, 0)

// ---------------------------------------------------------------------------
// Main loop: double-buffered A, one barrier per chunk. Wave covers 64 rows x
// 32 cols (nq) for steps s = s0, s0+4[, s0+8]. Per step: 4 A ds_reads,
// 2 pinned B frags, 4 MFMAs (2 row-tiles x 2 K16-halves).
// ---------------------------------------------------------------------------
template <int NS>
__device__ __forceinline__ void run_main(const float* __restrict__ xrow,
                                         const uint4* __restrict__ Bsw,
                                         uint4* __restrict__ Albuf,
                                         f32x16& acc0, f32x16& acc1,
                                         int s0, int nq, int l, int wr_off, int h) {
  const int hi = l >> 5;
  const int l31 = l & 31;
  float4 xa = *(const float4*)(xrow);
  build_half(xa, Albuf + wr_off, h);           // chunk 0 -> buf0
  xa = *(const float4*)(xrow + 32);            // x for chunk 1
  BARRIER();

  for (int c = 0; c < 32; ++c) {
    uint4* cur = Albuf + (c & 1) * 2304;
    uint4* nxt = Albuf + ((c + 1) & 1) * 2304;
    // ---- B fragments for this chunk's NS steps (L2-hot) -------------------
    uint4 Bv[NS][2];
#pragma unroll
    for (int i = 0; i < NS; ++i) {
      const uint4* wp = Bsw + (size_t)(((c * 9 + s0 + 4 * i) * 4 + nq) * 64) + l;
      Bv[i][0] = wp[0];       // u=0
      Bv[i][1] = wp[128];     // u=1 (+2*64)
    }
    // ---- builder for chunk c+1 into the other buffer ----------------------
    if (c + 1 < 32) {
      build_half(xa, nxt + wr_off, h);
      if (c + 2 < 32) xa = *(const float4*)(xrow + (c + 2) * 32);
    }
    // ---- pin B in regs: loads done by here, never re-issued ---------------
#pragma unroll
    for (int i = 0; i < NS; ++i) { KEEP4(Bv[i][0]); KEEP4(Bv[i][1]); }
    // ---- MFMA: wave's NS steps, 64 rows x 32 cols -------------------------
#pragma unroll
    for (int i = 0; i < NS; ++i) {
      const int s = s0 + 4 * i;
      const uint4* rb = cur + s * 256 + hi * 64 + l31;
      uint4 a00 = rb[0];      // u=0, rows l31      (run hi,   octet s)
      uint4 a01 = rb[32];     // u=0, rows l31+32
      uint4 a10 = rb[128];    // u=1, rows l31      (run 2+hi, octet s)
      uint4 a11 = rb[160];    // u=1, rows l31+32
      acc0 = MFMA32(a00, Bv[i][0], acc0);
      acc0 = MFMA32(a10, Bv[i][1], acc0);
      acc1 = MFMA32(a01, Bv[i][0], acc1);
      acc1 = MFMA32(a11, Bv[i][1], acc1);
    }
    BARRIER();   // writes to nxt visible; reads of cur drained
  }
}

// ---------------------------------------------------------------------------
// K2: 512 blocks x 512 thr. Block = 64 rows x 64 cols.
// MFMA wave w: nq = w&1 (col half), ks = w>>1 (K-step quarter).
// Builder role (unchanged): run r=w&3, half h=w>>2, row = lane.
// LDS: 2 x 36 KB A double-buffer; reused as 64 KB ks-partial store at end.
// ---------------------------------------------------------------------------
__global__ __launch_bounds__(512, 4) void wavelet_gemm(const float* __restrict__ x,
                                                       const uint4* __restrict__ Bsw,
                                                       float* __restrict__ out,
                                                       int out_size) {
  __shared__ uint4 Albuf[2 * 9 * 256];   // 72 KB
  const int tid = threadIdx.x;
  const int l = tid & 63;
  const int w = tid >> 6;            // wave 0..7
  const int nq = w & 1;              // col half
  const int ks = w >> 1;             // K-step quarter 0..3
  const int r = w & 3;               // builder run
  const int h = w >> 2;              // builder pair-half
  const int m = l;                   // builder row
  const long rowbase = (long)blockIdx.x * 64;
  const int wr_off = r * 64 + m;

  f32x16 acc0 = {};   // rows 0..31 of wave's 32-col half
  f32x16 acc1 = {};   // rows 32..63

  const float* xrow = x + (rowbase + m) * 1024 + r * 8 + h * 4;

  if (ks == 0) run_main<3>(xrow, Bsw, Albuf, acc0, acc1, 0, nq, l, wr_off, h);
  else         run_main<2>(xrow, Bsw, Albuf, acc0, acc1, ks, nq, l, wr_off, h);

  // ---- ks-partial store: P[ks][row 0..63][col 0..63] f32 = 64 KB ----------
  // 32x32 C/D layout: col=lane&31, row=(reg&3)+8*(reg>>2)+4*(lane>>5).
  float* P = (float*)Albuf;
  float* Pk = P + ks * 4096;
  const int col   = nq * 32 + (l & 31);
  const int rbase = 4 * (l >> 5);
#pragma unroll
  for (int rg = 0; rg < 16; ++rg) {
    const int grow = (rg & 3) + 8 * (rg >> 2) + rbase;
    Pk[grow * 64 + col]        = acc0[rg];
    Pk[(grow + 32) * 64 + col] = acc1[rg];
  }
  BARRIER();

  // ---- reduce 4 ks-partials, store: thread -> row=tid>>3, cols 8*(tid&7).. -
  float* og = out + (size_t)rowbase * 64;
  const int row = tid >> 3;
  const int cb  = (tid & 7) * 8;
  f32x4 v0 = *(const f32x4*)(P + row * 64 + cb);
  f32x4 v1 = *(const f32x4*)(P + row * 64 + cb + 4);
#pragma unroll
  for (int k = 1; k < 4; ++k) {
    v0 = v0 + *(const f32x4*)(P + k * 4096 + row * 64 + cb);
    v1 = v1 + *(const f32x4*)(P + k * 4096 + row * 64 + cb + 4);
  }
  *(f32x4*)(og + row * 64 + cb)     = v0;
  *(f32x4*)(og + row * 64 + cb + 4) = v1;
  if (blockIdx.x == 0 && tid == 0) out[out_size - 1] = 0.0f;  // kl = 0
}

extern "C" void kernel_launch(void* const* d_in, const int* in_sizes, int n_in,
                              void* d_out, int out_size, void* d_ws, size_t ws_size,
                              hipStream_t stream) {
  const float* x      = (const float*)d_in[0];   // [32768,1024] f32
  const float* coeffs = (const float*)d_in[1];   // [1024,64,8] f32
  const float* bw     = (const float*)d_in[2];   // [1024,64] f32
  uint4* Wsw = (uint4*)d_ws;                     // 288*4*64*16 = 1.125 MiB
  float* out = (float*)d_out;

  build_w<<<288, 256, 0, stream>>>(coeffs, bw, Wsw);
  wavelet_gemm<<<512, 512, 0, stream>>>(x, (const uint4*)Wsw, out, out_size);
}

// Round 4
// 225.279 us; speedup vs baseline: 1.0693x; 1.0001x over previous
//
#include <hip/hip_runtime.h>
#include <math.h>

// ============================================================================
// WaveletBasis as bf16 MFMA GEMM: M=32768(B), N=64(O), K=1024*9.
// K layout (ROUND 6, aligned): 128 "runs" of 72 k-values, run R = features
// [8R,8R+8). Run = 9 quads (qslot 0..8): qslot f<8 = basis n=0..7 of feature
// 8R+f; qslot 8 = x-quad (x of features 8R..8R+8, bf16-packed pairs).
// Chunk c = runs [4c,4c+4). A tile: uint4 idx = qslot*256 + run_local*64 +
// row. MFMA (s,u): K16 = qslot s of runs 2u+hi (hi = lane>>5).
//
// ROUND 6: round 5 (nq x ks waves, 32x32x16, B amp 1) hit 81.8us with
// MfmaUtil 18.6 / VALU 40 / stall 41%. Resource audit: MFMA 37K cyc/CU,
// LDS 54K, VALU ~20K/SIMD vs 196K wall -> schedule-bound, not pipe-bound:
// each wave ran builder THEN MFMA serially, barrier makes chunk = sum.
// This round:
//  - ROLE SPLIT: waves 0-3 = MFMA (nq=w&1 col half, ks=w>>1 step parity,
//    NS=5/4), waves 4-7 = builders (run r=w-4, full 8-feature row, 9 clean
//    b128 writes). Chunk cost -> max(builder, mfma); sides work on
//    different chunks; 1 barrier/chunk unchanged.
//  - aligned quad layout kills the dw[18] shuffle + uint2 tail writes.
//  - s_setprio(1) around MFMA cluster (T5: role-split makes it pay).
//  - ks-reduction now 2-way (32 KB partials in reused LDS).
// ============================================================================

typedef __attribute__((ext_vector_type(8))) short short8;
typedef __attribute__((ext_vector_type(4))) float f32x4;
typedef __attribute__((ext_vector_type(16))) float f32x16;

__device__ __forceinline__ unsigned int f2bf(float f) {
  unsigned int u = __float_as_uint(f);
  u += 0x7FFFu + ((u >> 16) & 1u);   // RNE; finite inputs
  return u >> 16;
}

// 4 dwords = 8 bf16 basis values (n=0..7) as a function of bucket j.
__device__ __forceinline__ void gen_basis(int j, unsigned int* d) {
  d[0] = (j < 4) ? 0x3F803F80u : 0xBF803F80u;                  // [phi=1, psi0=+-1]
  unsigned int sq1 = (j & 2) ? 0xBFB5u : 0x3FB5u;              // +-sqrt2
  d[1] = (j & 4) ? (sq1 << 16) : sq1;                          // one-hot k1=j>>2
  unsigned long long sd2 = (j & 1) ? 0xC000ull : 0x4000ull;    // +-2
  unsigned long long d23 = sd2 << ((j & 6) << 3);              // << 16*(j>>1)
  d[2] = (unsigned int)d23;
  d[3] = (unsigned int)(d23 >> 32);
}

#define BARRIER() __asm__ volatile("s_waitcnt lgkmcnt(0)\n\ts_barrier" ::: "memory")

// ---------------------------------------------------------------------------
// Builder: full run (8 features) for one row -> 8 basis quads + 1 x quad.
// dst already includes (run,row) offset; writes land at dst[qslot*256].
// Numerics unchanged (fast tanh + rare ref-fidelity fixer).
// ---------------------------------------------------------------------------
__device__ __forceinline__ void build_run(const float4& xa, const float4& xb,
                                          uint4* __restrict__ dst) {
  float xv[8] = {xa.x, xa.y, xa.z, xa.w, xb.x, xb.y, xb.z, xb.w};
  float t8v[8];
  unsigned int bad = 0;
#pragma unroll
  for (int ff = 0; ff < 8; ++ff) {
    float e = __expf(2.0f * xv[ff]);                 // t8 = 8*e/(e+1) = 8 - 8/(e+1)
    float r = __builtin_amdgcn_rcpf(e + 1.0f);
    float t8 = __builtin_fmaf(-8.0f, r, 8.0f);
    float rn = rintf(t8);
    if (fabsf(t8 - rn) < 3e-5f) bad |= 1u << ff;
    t8v[ff] = t8;
  }
  if (__builtin_expect(bad != 0, 0)) {
#pragma unroll
    for (int ff = 0; ff < 8; ++ff)
      if (bad & (1u << ff)) {
        float tf = (float)tanh((double)xv[ff]);      // ref-fidelity fallback
        t8v[ff] = ((tf + 1.0f) * 0.5f) * 8.0f;       // exact ref f32 pipeline
      }
  }
#pragma unroll
  for (int ff = 0; ff < 8; ++ff) {
    int j = (int)t8v[ff]; j = j > 7 ? 7 : j;         // t8 in [0,8]
    unsigned int d[4];
    gen_basis(j, d);
    uint4 qv; qv.x = d[0]; qv.y = d[1]; qv.z = d[2]; qv.w = d[3];
    dst[ff * 256] = qv;
  }
  uint4 xq;
  xq.x = f2bf(xv[0]) | (f2bf(xv[1]) << 16);
  xq.y = f2bf(xv[2]) | (f2bf(xv[3]) << 16);
  xq.z = f2bf(xv[4]) | (f2bf(xv[5]) << 16);
  xq.w = f2bf(xv[6]) | (f2bf(xv[7]) << 16);
  dst[8 * 256] = xq;
}

// ---------------------------------------------------------------------------
// K1: W into 32x32x16 B-fragment order under the ALIGNED run layout.
// Fragment (c,s,u,nq) at Bsw[((c*9+s)*4 + 2u + nq)*64 + l]: lane l holds
// col o = 32nq+(l&31), k = qslot s of run R = 4c+2u+(l>>5). Short jj of the
// octet: s<8 -> (f=8R+s, n=jj); s==8 -> (f=8R+jj, n=8 i.e. base_weight).
// ---------------------------------------------------------------------------
__global__ __launch_bounds__(256) void build_w(const float* __restrict__ coeffs,
                                               const float* __restrict__ bw,
                                               uint4* __restrict__ Wsw) {
  const int l = threadIdx.x & 63;
  const int t = threadIdx.x >> 6;   // t = 2u+nq, 0..3
  const int g = blockIdx.x;         // 0..287
  const int c = g / 9, j = g - c * 9;
  const int u = t >> 1, nq = t & 1;
  const int R = c * 4 + 2 * u + (l >> 5);
  const int o = nq * 32 + (l & 31);
  unsigned int dwv[4];
#pragma unroll
  for (int jj = 0; jj < 8; ++jj) {
    int f, n;
    if (j < 8) { f = 8 * R + j;  n = jj; }
    else       { f = 8 * R + jj; n = 8;  }
    float v = (n < 8) ? coeffs[(f * 64 + o) * 8 + n] : bw[f * 64 + o];
    unsigned int hh = f2bf(v);
    if (jj & 1) dwv[jj >> 1] |= hh << 16; else dwv[jj >> 1] = hh;
  }
  uint4 qq; qq.x = dwv[0]; qq.y = dwv[1]; qq.z = dwv[2]; qq.w = dwv[3];
  Wsw[(g * 4 + t) * 64 + l] = qq;
}

#define MFMA32(A, B, C) __builtin_amdgcn_mfma_f32_32x32x16_bf16( \
    __builtin_bit_cast(short8, (A)), __builtin_bit_cast(short8, (B)), (C), 0, 0, 0)

// ---------------------------------------------------------------------------
// MFMA-wave main loop. Steps s = ks, ks+2, ... (NS of them); 64 rows x 32
// cols (nq half). Per step: 4 A ds_reads, 2 B frags, 4 MFMAs.
// Matches builder barrier count: 1 prologue + 32 in-loop.
// ---------------------------------------------------------------------------
template <int NS>
__device__ __forceinline__ void mfma_main(const uint4* __restrict__ Bsw,
                                          const uint4* __restrict__ Albuf,
                                          f32x16& acc0, f32x16& acc1,
                                          int ks, int nq, int l) {
  const int hi = l >> 5;
  const int l31 = l & 31;
  BARRIER();                                   // chunk 0 built
  for (int c = 0; c < 32; ++c) {
    const uint4* cur = Albuf + (c & 1) * 2304;
    uint4 Bv[NS][2];
#pragma unroll
    for (int i = 0; i < NS; ++i) {
      const uint4* wp = Bsw + (size_t)(((c * 9 + ks + 2 * i) * 4 + nq) * 64) + l;
      Bv[i][0] = wp[0];       // u=0
      Bv[i][1] = wp[128];     // u=1
    }
    __builtin_amdgcn_s_setprio(1);
#pragma unroll
    for (int i = 0; i < NS; ++i) {
      const int s = ks + 2 * i;
      const uint4* rb = cur + s * 256 + hi * 64 + l31;
      uint4 a00 = rb[0];      // u=0, rows l31
      uint4 a01 = rb[32];     // u=0, rows l31+32
      uint4 a10 = rb[128];    // u=1, rows l31
      uint4 a11 = rb[160];    // u=1, rows l31+32
      acc0 = MFMA32(a00, Bv[i][0], acc0);
      acc0 = MFMA32(a10, Bv[i][1], acc0);
      acc1 = MFMA32(a01, Bv[i][0], acc1);
      acc1 = MFMA32(a11, Bv[i][1], acc1);
    }
    __builtin_amdgcn_s_setprio(0);
    BARRIER();
  }
}

// ---------------------------------------------------------------------------
// K2: 512 blocks x 512 thr. Block = 64 rows x 64 cols.
// Waves 0-3: MFMA (nq = w&1 col half, ks = w>>1 step parity, NS=5/4).
// Waves 4-7: builders (run r = w-4, row = lane, full 8-feature run).
// LDS: 2 x 36 KB A double-buffer; low 32 KB reused as 2 ks-partials at end.
// ---------------------------------------------------------------------------
__global__ __launch_bounds__(512, 4) void wavelet_gemm(const float* __restrict__ x,
                                                       const uint4* __restrict__ Bsw,
                                                       float* __restrict__ out,
                                                       int out_size) {
  __shared__ uint4 Albuf[2 * 9 * 256];   // 72 KB
  const int tid = threadIdx.x;
  const int l = tid & 63;
  const int w = tid >> 6;            // wave 0..7
  const long rowbase = (long)blockIdx.x * 64;
  float* P = (float*)Albuf;          // epilogue partials (32 KB, reused)

  if (w < 4) {
    // ---------------- MFMA waves ----------------
    const int nq = w & 1;
    const int ks = w >> 1;           // 0: steps {0,2,4,6,8}; 1: {1,3,5,7}
    f32x16 acc0 = {};                // rows 0..31 of the 32-col half
    f32x16 acc1 = {};                // rows 32..63
    if (ks == 0) mfma_main<5>(Bsw, Albuf, acc0, acc1, 0, nq, l);
    else         mfma_main<4>(Bsw, Albuf, acc0, acc1, 1, nq, l);
    // ks-partial store: P[ks][row][col], 32x32 C/D layout:
    // col=lane&31, row=(reg&3)+8*(reg>>2)+4*(lane>>5).
    float* Pk = P + ks * 4096;
    const int col   = nq * 32 + (l & 31);
    const int rbase = 4 * (l >> 5);
#pragma unroll
    for (int rg = 0; rg < 16; ++rg) {
      const int grow = (rg & 3) + 8 * (rg >> 2) + rbase;
      Pk[grow * 64 + col]        = acc0[rg];
      Pk[(grow + 32) * 64 + col] = acc1[rg];
    }
    BARRIER();                       // partials visible
  } else {
    // ---------------- builder waves ----------------
    const int r = w - 4;             // run within chunk
    uint4* wr0 = Albuf + r * 64 + l;
    const float* xrow = x + (rowbase + l) * 1024 + r * 8;
    float4 xa = *(const float4*)(xrow);
    float4 xb = *(const float4*)(xrow + 4);
    build_run(xa, xb, wr0);          // chunk 0 -> buf0
    xa = *(const float4*)(xrow + 32);
    xb = *(const float4*)(xrow + 36);
    BARRIER();                       // chunk 0 ready
    for (int c = 0; c < 32; ++c) {
      if (c + 1 < 32) {
        build_run(xa, xb, Albuf + ((c + 1) & 1) * 2304 + r * 64 + l);
        if (c + 2 < 32) {
          xa = *(const float4*)(xrow + (c + 2) * 32);
          xb = *(const float4*)(xrow + (c + 2) * 32 + 4);
        }
      }
      BARRIER();
    }
    BARRIER();                       // wait for MFMA partials
  }

  // ---- joint reduction: out = P[0] + P[1]; thread -> row=tid>>3, 8 cols ---
  float* og = out + (size_t)rowbase * 64;
  const int row = tid >> 3;
  const int cb  = (tid & 7) * 8;
  f32x4 v0 = *(const f32x4*)(P + row * 64 + cb);
  f32x4 v1 = *(const f32x4*)(P + row * 64 + cb + 4);
  v0 = v0 + *(const f32x4*)(P + 4096 + row * 64 + cb);
  v1 = v1 + *(const f32x4*)(P + 4096 + row * 64 + cb + 4);
  *(f32x4*)(og + row * 64 + cb)     = v0;
  *(f32x4*)(og + row * 64 + cb + 4) = v1;
  if (blockIdx.x == 0 && tid == 0) out[out_size - 1] = 0.0f;  // kl = 0
}

extern "C" void kernel_launch(void* const* d_in, const int* in_sizes, int n_in,
                              void* d_out, int out_size, void* d_ws, size_t ws_size,
                              hipStream_t stream) {
  const float* x      = (const float*)d_in[0];   // [32768,1024] f32
  const float* coeffs = (const float*)d_in[1];   // [1024,64,8] f32
  const float* bw     = (const float*)d_in[2];   // [1024,64] f32
  uint4* Wsw = (uint4*)d_ws;                     // 288*4*64*16 = 1.125 MiB
  float* out = (float*)d_out;

  build_w<<<288, 256, 0, stream>>>(coeffs, bw, Wsw);
  wavelet_gemm<<<512, 512, 0, stream>>>(x, (const uint4*)Wsw, out, out_size);
}